// Round 1
// baseline (195.710 us; speedup 1.0000x reference)
//
#include <hip/hip_runtime.h>
#include <math.h>

#define NB 4
#define ND 96
#define NN 512
#define NA 256

static constexpr float C_TANH = 2.8853900817779268f; // 2*log2(e)
static constexpr float LOG2E  = 1.4426950408889634f;

__device__ __forceinline__ float fexp2(float x) {
#if __has_builtin(__builtin_amdgcn_exp2f)
  return __builtin_amdgcn_exp2f(x);
#else
  return exp2f(x);
#endif
}
__device__ __forceinline__ float frcp(float x) {
#if __has_builtin(__builtin_amdgcn_rcpf)
  return __builtin_amdgcn_rcpf(x);
#else
  return 1.0f / x;
#endif
}

// --- k0: transpose Wg1,Wg2 -> [d][a] for coalesced reads in k_proj
__global__ __launch_bounds__(256) void k_wt(const float* __restrict__ Wg1,
                                            const float* __restrict__ Wg2,
                                            float* __restrict__ W1t,
                                            float* __restrict__ W2t) {
  int idx = blockIdx.x * 256 + threadIdx.x;   // 0 .. 2*96*256-1
  int mat = idx / (ND * NA);
  int rem = idx - mat * (ND * NA);
  int d = rem >> 8;
  int a = rem & 255;
  const float* s = mat ? Wg2 : Wg1;
  float* t = mat ? W2t : W1t;
  t[d * NA + a] = s[a * ND + d];
}

// --- k0b: S0 = sum(Wa_w) + Wa_b + ba
__global__ __launch_bounds__(256) void k_s0(const float* __restrict__ Wa_w,
                                            const float* __restrict__ Wa_b,
                                            const float* __restrict__ ba,
                                            float* __restrict__ S0) {
  __shared__ float red[256];
  int t = threadIdx.x;
  red[t] = Wa_w[t];
  __syncthreads();
  for (int s = 128; s > 0; s >>= 1) {
    if (t < s) red[t] += red[t + s];
    __syncthreads();
  }
  if (t == 0) S0[0] = red[0] + Wa_b[0] + ba[0];
}

// --- k1: G1[b,n,a] = C*(sum_d x[b,d,n]*Wg1[a,d] + bg[a]), G2 likewise (no bias),
//         and xt[b,n,d] = x[b,d,n].  Block = (b, 8 n's), thread = a.
__global__ __launch_bounds__(256) void k_proj(const float* __restrict__ x,
                                              const float* __restrict__ W1t,
                                              const float* __restrict__ W2t,
                                              const float* __restrict__ bg,
                                              float* __restrict__ G1,
                                              float* __restrict__ G2,
                                              float* __restrict__ xt) {
  __shared__ float xsh[8][ND];
  const int tid = threadIdx.x;
  const int b = blockIdx.x >> 6;
  const int n0 = (blockIdx.x & 63) * 8;

  for (int idx = tid; idx < 8 * ND; idx += 256) {
    int d = idx >> 3, j = idx & 7;
    float v = x[(size_t)(b * ND + d) * NN + n0 + j];
    xsh[j][d] = v;
    xt[(size_t)(b * NN + n0 + j) * ND + d] = v;
  }
  __syncthreads();

  const int a = tid;
  float acc1[8], acc2[8];
  float bgv = bg[a];
#pragma unroll
  for (int j = 0; j < 8; ++j) { acc1[j] = bgv; acc2[j] = 0.f; }

  for (int d = 0; d < ND; ++d) {
    float w1 = W1t[d * NA + a];
    float w2 = W2t[d * NA + a];
#pragma unroll
    for (int j = 0; j < 8; ++j) {
      float xv = xsh[j][d];
      acc1[j] = fmaf(w1, xv, acc1[j]);
      acc2[j] = fmaf(w2, xv, acc2[j]);
    }
  }
#pragma unroll
  for (int j = 0; j < 8; ++j) {
    G1[(size_t)(b * NN + n0 + j) * NA + a] = C_TANH * acc1[j];
    G2[(size_t)(b * NN + n0 + j) * NA + a] = C_TANH * acc2[j];
  }
}

// --- k2: fused pairwise-tanh attention + AV.
// Block = (b, 4 n's), 256 threads. Thread owns one m per m-pass (2 passes of 256 m).
// a-loop in 4 chunks of 64; G2 chunk staged in LDS with XOR-swizzle (q ^ (r&7))
// so the row-stride-256B ds_read_b128 pattern is conflict-free.
__global__ __launch_bounds__(256, 2) void k_main(const float* __restrict__ G1,
                                                 const float* __restrict__ G2,
                                                 const float* __restrict__ xt,
                                                 const float* __restrict__ Wa_w,
                                                 const float* __restrict__ S0p,
                                                 float* __restrict__ out) {
  __shared__ float4 g2sh[4096];      // 64KB: 256 rows x 16 float4 (a-chunk = 64)
  __shared__ float attsh[4][NN];     // 8KB
  const int tid = threadIdx.x;
  const int b = blockIdx.x >> 7;
  const int n0 = (blockIdx.x & 127) << 2;
  const float S0 = S0p[0];
  const float4* __restrict__ W4 = (const float4*)Wa_w;
  const float* __restrict__ g1r0 = G1 + (size_t)(b * NN + n0) * NA;

  for (int p = 0; p < 2; ++p) {
    float acc[4] = {0.f, 0.f, 0.f, 0.f};
    const float4* __restrict__ srcbase = (const float4*)(G2 + (size_t)(b * NN + p * 256) * NA);
    for (int c = 0; c < 4; ++c) {
      __syncthreads();
      const float4* __restrict__ src = srcbase + c * 16;  // +c*64 floats
#pragma unroll
      for (int k = 0; k < 16; ++k) {
        int f = k * 256 + tid;
        int r = f >> 4;        // row (m within tile)
        int q = f & 15;        // 16B granule within 64-float chunk
        g2sh[r * 16 + (q ^ (r & 7))] = src[r * 64 + q];
      }
      __syncthreads();
      const int a0 = c * 64;
#pragma unroll
      for (int k4 = 0; k4 < 16; ++k4) {
        float4 v = g2sh[tid * 16 + (k4 ^ (tid & 7))];
        float g2v[4] = {v.x, v.y, v.z, v.w};
        float4 wq = W4[(a0 >> 2) + k4];
        float wv[4] = {wq.x, wq.y, wq.z, wq.w};
        float g1v[4][4];
#pragma unroll
        for (int nl = 0; nl < 4; ++nl) {
          float4 g = *(const float4*)(g1r0 + nl * NA + a0 + k4 * 4);
          g1v[nl][0] = g.x; g1v[nl][1] = g.y; g1v[nl][2] = g.z; g1v[nl][3] = g.w;
        }
#pragma unroll
        for (int j = 0; j < 4; ++j) {
#pragma unroll
          for (int nl = 0; nl < 4; ++nl) {
            float e = fexp2(g1v[nl][j] + g2v[j]);     // exp2(C*(g1+g2+bg))
            acc[nl] = fmaf(wv[j], frcp(1.f + e), acc[nl]);
          }
        }
      }
    }
    // score = sigmoid(S0 - 2*acc)
#pragma unroll
    for (int nl = 0; nl < 4; ++nl) {
      float z = S0 - 2.f * acc[nl];
      attsh[nl][p * 256 + tid] = frcp(1.f + fexp2(-LOG2E * z));
    }
  }
  __syncthreads();

  // AV: wave w handles row n0+w; lane l covers d=l and d=64+(l&31)
  const int w = tid >> 6;
  const int l = tid & 63;
  const float* __restrict__ xb = xt + (size_t)b * NN * ND;
  const float* __restrict__ arow = attsh[w];
  float o0 = 0.f, o1 = 0.f;
  for (int m = 0; m < NN; ++m) {
    float av = arow[m];
    const float* xr = xb + m * ND;
    o0 = fmaf(av, xr[l], o0);
    o1 = fmaf(av, xr[64 + (l & 31)], o1);
  }
  float* orow = out + (size_t)(b * NN + n0 + w) * ND;
  orow[l] = o0;
  if (l < 32) orow[64 + l] = o1;
}

extern "C" void kernel_launch(void* const* d_in, const int* in_sizes, int n_in,
                              void* d_out, int out_size, void* d_ws, size_t ws_size,
                              hipStream_t stream) {
  const float* x    = (const float*)d_in[0];
  const float* Wg1  = (const float*)d_in[1];
  const float* Wg2  = (const float*)d_in[2];
  const float* bg   = (const float*)d_in[3];
  const float* Wa_w = (const float*)d_in[4];
  const float* Wa_b = (const float*)d_in[5];
  const float* ba   = (const float*)d_in[6];
  float* out = (float*)d_out;

  float* ws  = (float*)d_ws;
  float* G1  = ws;                 // 4*512*256 = 524288 floats
  float* G2  = ws + 524288;        // 524288
  float* xtw = ws + 1048576;       // 4*512*96 = 196608
  float* W1t = ws + 1245184;       // 96*256 = 24576
  float* W2t = ws + 1269760;       // 24576
  float* S0  = ws + 1294336;       // 1    (total ~5.2 MB)

  hipLaunchKernelGGL(k_wt,   dim3(192), dim3(256), 0, stream, Wg1, Wg2, W1t, W2t);
  hipLaunchKernelGGL(k_s0,   dim3(1),   dim3(256), 0, stream, Wa_w, Wa_b, ba, S0);
  hipLaunchKernelGGL(k_proj, dim3(256), dim3(256), 0, stream, x, W1t, W2t, bg, G1, G2, xtw);
  hipLaunchKernelGGL(k_main, dim3(512), dim3(256), 0, stream, G1, G2, xtw, Wa_w, S0, out);
}

// Round 2
// 169.833 us; speedup vs baseline: 1.1524x; 1.1524x over previous
//
#include <hip/hip_runtime.h>
#include <math.h>

#define NB 4
#define ND 96
#define NN 512
#define NA 256

static constexpr float C_TANH = 2.8853900817779268f; // 2*log2(e)
static constexpr float LOG2E  = 1.4426950408889634f;

__device__ __forceinline__ float fexp2(float x) {
#if __has_builtin(__builtin_amdgcn_exp2f)
  return __builtin_amdgcn_exp2f(x);
#else
  return exp2f(x);
#endif
}
__device__ __forceinline__ float frcp(float x) {
#if __has_builtin(__builtin_amdgcn_rcpf)
  return __builtin_amdgcn_rcpf(x);
#else
  return 1.0f / x;
#endif
}

// --- k_prep: blocks 0..191 transpose Wg1/Wg2 -> [d][a]; block 192 reduces S0.
__global__ __launch_bounds__(256) void k_prep(const float* __restrict__ Wg1,
                                              const float* __restrict__ Wg2,
                                              const float* __restrict__ Wa_w,
                                              const float* __restrict__ Wa_b,
                                              const float* __restrict__ ba,
                                              float* __restrict__ W1t,
                                              float* __restrict__ W2t,
                                              float* __restrict__ S0) {
  if (blockIdx.x == 192) {
    __shared__ float red[256];
    int t = threadIdx.x;
    red[t] = Wa_w[t];
    __syncthreads();
    for (int s = 128; s > 0; s >>= 1) {
      if (t < s) red[t] += red[t + s];
      __syncthreads();
    }
    if (t == 0) S0[0] = red[0] + Wa_b[0] + ba[0];
    return;
  }
  int idx = blockIdx.x * 256 + threadIdx.x;  // 0 .. 2*96*256-1
  int mat = idx / (ND * NA);
  int rem = idx - mat * (ND * NA);
  int d = rem >> 8;
  int a = rem & 255;
  (mat ? W2t : W1t)[d * NA + a] = (mat ? Wg2 : Wg1)[a * ND + d];
}

// --- k_proj: G1[b,n,a] = C*(x.Wg1 + bg), G2 (chunk-major) = C*(x.Wg2), xt = transpose.
// Block = (b, 4 n's), thread = a. 512 blocks -> 2 blocks/CU.
__global__ __launch_bounds__(256, 2) void k_proj(const float* __restrict__ x,
                                                 const float* __restrict__ W1t,
                                                 const float* __restrict__ W2t,
                                                 const float* __restrict__ bg,
                                                 float* __restrict__ G1,
                                                 float* __restrict__ G2c,
                                                 float* __restrict__ xt) {
  __shared__ float4 xsh[ND];  // xsh[d] = x[b, d, n0..n0+3]
  const int tid = threadIdx.x;
  const int b = blockIdx.x >> 7;
  const int n0 = (blockIdx.x & 127) * 4;

  for (int idx = tid; idx < ND * 4; idx += 256) {
    int d = idx >> 2, j = idx & 3;
    float v = x[(size_t)(b * ND + d) * NN + n0 + j];
    ((float*)&xsh[d])[j] = v;
    xt[(size_t)(b * NN + n0 + j) * ND + d] = v;
  }
  __syncthreads();

  const int a = tid;
  const float bgv = bg[a];
  float acc1[4], acc2[4];
#pragma unroll
  for (int j = 0; j < 4; ++j) { acc1[j] = bgv; acc2[j] = 0.f; }

  for (int d4 = 0; d4 < ND / 4; ++d4) {
    float w1[4], w2[4];
#pragma unroll
    for (int dd = 0; dd < 4; ++dd) {
      w1[dd] = W1t[(d4 * 4 + dd) * NA + a];
      w2[dd] = W2t[(d4 * 4 + dd) * NA + a];
    }
#pragma unroll
    for (int dd = 0; dd < 4; ++dd) {
      float4 xq = xsh[d4 * 4 + dd];
      float xv[4] = {xq.x, xq.y, xq.z, xq.w};
#pragma unroll
      for (int j = 0; j < 4; ++j) {
        acc1[j] = fmaf(w1[dd], xv[j], acc1[j]);
        acc2[j] = fmaf(w2[dd], xv[j], acc2[j]);
      }
    }
  }
  const int c = a >> 5, al = a & 31;
#pragma unroll
  for (int j = 0; j < 4; ++j) {
    G1[(size_t)(b * NN + n0 + j) * NA + a] = C_TANH * acc1[j];
    // chunk-major: G2c[b][c][n][al] -> k_main stages one contiguous 32KB block
    G2c[((size_t)(b * 8 + c) * NN + n0 + j) * 32 + al] = C_TANH * acc2[j];
  }
}

// --- k_main: fused pairwise-tanh attention + AV.
// Block = (b, 4 n's), 256 threads, 2 m-passes of 256. a-chunk = 32 floats,
// g2sh = 32KB (XOR-swizzled), attsh = 8KB -> 40KB LDS -> 4 blocks/CU.
__global__ __launch_bounds__(256, 4) void k_main(const float* __restrict__ G1,
                                                 const float* __restrict__ G2c,
                                                 const float* __restrict__ xt,
                                                 const float* __restrict__ Wa_w,
                                                 const float* __restrict__ S0p,
                                                 float* __restrict__ out) {
  __shared__ float4 g2sh[256 * 8];   // 32 KB: 256 rows x 8 float4
  __shared__ float attsh[4][NN];     // 8 KB
  const int tid = threadIdx.x;
  const int b = blockIdx.x >> 7;
  const int n0 = (blockIdx.x & 127) << 2;
  const float S0 = S0p[0];
  const float4* __restrict__ W4 = (const float4*)Wa_w;
  const float* __restrict__ g1r0 = G1 + (size_t)(b * NN + n0) * NA;

  for (int p = 0; p < 2; ++p) {
    float acc[4] = {0.f, 0.f, 0.f, 0.f};
    for (int c = 0; c < 8; ++c) {
      const float4* __restrict__ src =
          (const float4*)(G2c + ((size_t)(b * 8 + c) * NN + p * 256) * 32);
      __syncthreads();
#pragma unroll
      for (int k = 0; k < 8; ++k) {
        int f = k * 256 + tid;
        int r = f >> 3, q = f & 7;
        g2sh[r * 8 + (q ^ (r & 7))] = src[f];   // fully-coalesced 32KB stage
      }
      __syncthreads();
#pragma unroll
      for (int k4 = 0; k4 < 8; ++k4) {
        float4 v = g2sh[tid * 8 + (k4 ^ (tid & 7))];
        float g2v[4] = {v.x, v.y, v.z, v.w};
        float4 wq = W4[c * 8 + k4];
        float wv[4] = {wq.x, wq.y, wq.z, wq.w};
#pragma unroll
        for (int nl = 0; nl < 4; ++nl) {
          float4 g = *(const float4*)(g1r0 + nl * NA + c * 32 + k4 * 4);
          float g1v[4] = {g.x, g.y, g.z, g.w};
#pragma unroll
          for (int j = 0; j < 4; ++j) {
            float e = fexp2(g1v[j] + g2v[j]);          // exp2(C*(g1+g2+bg))
            acc[nl] = fmaf(wv[j], frcp(1.f + e), acc[nl]);
          }
        }
      }
    }
#pragma unroll
    for (int nl = 0; nl < 4; ++nl) {
      float z = S0 - 2.f * acc[nl];
      attsh[nl][p * 256 + tid] = frcp(1.f + fexp2(-LOG2E * z));  // sigmoid
    }
  }
  __syncthreads();

  // AV: wave w handles row n0+w; lane l covers d=l and d=64+(l&31)
  const int w = tid >> 6;
  const int l = tid & 63;
  const float* __restrict__ xb = xt + (size_t)b * NN * ND;
  const float* __restrict__ arow = attsh[w];
  float o0 = 0.f, o1 = 0.f;
  for (int m = 0; m < NN; ++m) {
    float av = arow[m];
    const float* xr = xb + m * ND;
    o0 = fmaf(av, xr[l], o0);
    o1 = fmaf(av, xr[64 + (l & 31)], o1);
  }
  float* orow = out + (size_t)(b * NN + n0 + w) * ND;
  orow[l] = o0;
  if (l < 32) orow[64 + l] = o1;
}

extern "C" void kernel_launch(void* const* d_in, const int* in_sizes, int n_in,
                              void* d_out, int out_size, void* d_ws, size_t ws_size,
                              hipStream_t stream) {
  const float* x    = (const float*)d_in[0];
  const float* Wg1  = (const float*)d_in[1];
  const float* Wg2  = (const float*)d_in[2];
  const float* bg   = (const float*)d_in[3];
  const float* Wa_w = (const float*)d_in[4];
  const float* Wa_b = (const float*)d_in[5];
  const float* ba   = (const float*)d_in[6];
  float* out = (float*)d_out;

  float* ws  = (float*)d_ws;
  float* G1  = ws;                 // 4*512*256 = 524288 floats
  float* G2c = ws + 524288;        // 524288 (chunk-major)
  float* xtw = ws + 1048576;       // 4*512*96 = 196608
  float* W1t = ws + 1245184;       // 96*256 = 24576
  float* W2t = ws + 1269760;       // 24576
  float* S0  = ws + 1294336;       // 1   (total ~5.2 MB)

  hipLaunchKernelGGL(k_prep, dim3(193), dim3(256), 0, stream,
                     Wg1, Wg2, Wa_w, Wa_b, ba, W1t, W2t, S0);
  hipLaunchKernelGGL(k_proj, dim3(512), dim3(256), 0, stream,
                     x, W1t, W2t, bg, G1, G2c, xtw);
  hipLaunchKernelGGL(k_main, dim3(512), dim3(256), 0, stream,
                     G1, G2c, xtw, Wa_w, S0, out);
}